// Round 1
// baseline (519.911 us; speedup 1.0000x reference)
//
#include <hip/hip_runtime.h>

#define NN 50000      // nodes
#define NE 800000     // edges
#define F  64         // feature dim
#define AT_STRIDE 68  // padded LDS stride for transposed tiles (mult of 4, not mult of 32)

// ---------------- CSR build ----------------

__global__ void k_count(const int* __restrict__ dst, int* __restrict__ cnt) {
    int e = blockIdx.x * blockDim.x + threadIdx.x;
    if (e < NE) atomicAdd(&cnt[dst[e]], 1);
}

__global__ void k_scan(const int* __restrict__ cnt, int* __restrict__ offs) {
    const int T = 1024;
    const int CH = (NN + T - 1) / T;  // 49
    __shared__ int sc[T];
    int t = threadIdx.x;
    int beg = t * CH;
    int end = beg + CH < NN ? beg + CH : NN;
    int s = 0;
    for (int i = beg; i < end; ++i) s += cnt[i];
    sc[t] = s;
    __syncthreads();
    for (int d = 1; d < T; d <<= 1) {
        int v = (t >= d) ? sc[t - d] : 0;
        __syncthreads();
        sc[t] += v;
        __syncthreads();
    }
    int run = sc[t] - s;  // exclusive prefix of this chunk
    for (int i = beg; i < end; ++i) { offs[i] = run; run += cnt[i]; }
    if (t == T - 1) offs[NN] = sc[T - 1];
}

__global__ void k_fill(const int* __restrict__ src, const int* __restrict__ dst,
                       const int* __restrict__ offs, int* __restrict__ cursor,
                       int* __restrict__ csr_src) {
    int e = blockIdx.x * blockDim.x + threadIdx.x;
    if (e < NE) {
        int d = dst[e];
        int p = atomicAdd(&cursor[d], 1);
        csr_src[offs[d] + p] = src[e];
    }
}

// ---------------- embedding gather (item_ids lookup) ----------------

__global__ void k_gather(const float* __restrict__ embed, const int* __restrict__ ids,
                         float* __restrict__ x) {
    int t = blockIdx.x * blockDim.x + threadIdx.x;  // over NN*16 float4s
    if (t < NN * 16) {
        int i = t >> 4, c = t & 15;
        ((float4*)x)[t] = ((const float4*)embed)[ids[i] * 16 + c];
    }
}

// ---------------- fused SAGE layer: mean-agg + (A@Ws + N@Wn + b) ----------------
// block = 256 threads, 64 nodes per block.

template <bool RELU>
__launch_bounds__(256)
__global__ void k_layer(const float* __restrict__ in, const int* __restrict__ offs,
                        const int* __restrict__ csr_src,
                        const float* __restrict__ Ws, const float* __restrict__ Wn,
                        const float* __restrict__ b, float* __restrict__ out) {
    __shared__ float AsT[F * AT_STRIDE];  // transposed: AsT[k][node]
    __shared__ float NsT[F * AT_STRIDE];
    __shared__ float WsL[F * F];
    __shared__ float WnL[F * F];

    const int tid = threadIdx.x;
    const int node0 = blockIdx.x * 64;

    // stage weights (row-major [k][f], as given)
    for (int idx = tid; idx < F * F; idx += 256) {
        WsL[idx] = Ws[idx];
        WnL[idx] = Wn[idx];
    }
    // stage self-features, transposed
    for (int idx = tid; idx < 64 * F; idx += 256) {
        int n = idx >> 6, f = idx & 63;
        int node = node0 + n;
        AsT[f * AT_STRIDE + n] = (node < NN) ? in[node * 64 + f] : 0.f;
    }

    // neighbor mean-aggregation: wave per node, lane = feature
    const int wave = tid >> 6, lane = tid & 63;
    for (int t2 = 0; t2 < 16; ++t2) {
        int nl = wave * 16 + t2;
        int node = node0 + nl;
        float s = 0.f;
        if (node < NN) {
            int beg = offs[node], end = offs[node + 1];
            int j = beg;
            for (; j + 3 < end; j += 4) {  // unroll for MLP (independent loads)
                int s0 = csr_src[j], s1 = csr_src[j + 1];
                int s2 = csr_src[j + 2], s3 = csr_src[j + 3];
                s += in[s0 * 64 + lane] + in[s1 * 64 + lane] +
                     in[s2 * 64 + lane] + in[s3 * 64 + lane];
            }
            for (; j < end; ++j) s += in[csr_src[j] * 64 + lane];
            int deg = end - beg;
            s = (deg > 0) ? s * (1.f / (float)deg) : 0.f;
        }
        NsT[lane * AT_STRIDE + nl] = s;
    }
    __syncthreads();

    // GEMM: 16x16 threads, each a 4(node) x 4(feat) microtile
    const int tx = tid & 15, ty = tid >> 4;
    float acc[4][4];
#pragma unroll
    for (int j = 0; j < 4; ++j) {
        float bv = b[4 * tx + j];
        acc[0][j] = bv; acc[1][j] = bv; acc[2][j] = bv; acc[3][j] = bv;
    }
#pragma unroll 4
    for (int k = 0; k < 64; ++k) {
        float4 a4 = *(const float4*)&AsT[k * AT_STRIDE + 4 * ty];
        float4 n4 = *(const float4*)&NsT[k * AT_STRIDE + 4 * ty];
        float4 w4 = *(const float4*)&WsL[k * 64 + 4 * tx];
        float4 u4 = *(const float4*)&WnL[k * 64 + 4 * tx];
        float a_[4] = {a4.x, a4.y, a4.z, a4.w};
        float n_[4] = {n4.x, n4.y, n4.z, n4.w};
        float w_[4] = {w4.x, w4.y, w4.z, w4.w};
        float u_[4] = {u4.x, u4.y, u4.z, u4.w};
#pragma unroll
        for (int i = 0; i < 4; ++i)
#pragma unroll
            for (int j = 0; j < 4; ++j)
                acc[i][j] += a_[i] * w_[j] + n_[i] * u_[j];
    }

#pragma unroll
    for (int i = 0; i < 4; ++i) {
        int node = node0 + 4 * ty + i;
        if (node < NN) {
            float4 o;
            o.x = acc[i][0]; o.y = acc[i][1]; o.z = acc[i][2]; o.w = acc[i][3];
            if (RELU) {
                o.x = o.x > 0.f ? o.x : 0.f;
                o.y = o.y > 0.f ? o.y : 0.f;
                o.z = o.z > 0.f ? o.z : 0.f;
                o.w = o.w > 0.f ? o.w : 0.f;
            }
            *(float4*)&out[node * 64 + 4 * tx] = o;
        }
    }
}

// ---------------- final linear: out = H @ W_fc + b_fc ----------------

__launch_bounds__(256)
__global__ void k_final(const float* __restrict__ in, const float* __restrict__ W,
                        const float* __restrict__ b, float* __restrict__ out) {
    __shared__ float AsT[F * AT_STRIDE];
    __shared__ float WL[F * F];

    const int tid = threadIdx.x;
    const int node0 = blockIdx.x * 64;

    for (int idx = tid; idx < F * F; idx += 256) WL[idx] = W[idx];
    for (int idx = tid; idx < 64 * F; idx += 256) {
        int n = idx >> 6, f = idx & 63;
        int node = node0 + n;
        AsT[f * AT_STRIDE + n] = (node < NN) ? in[node * 64 + f] : 0.f;
    }
    __syncthreads();

    const int tx = tid & 15, ty = tid >> 4;
    float acc[4][4];
#pragma unroll
    for (int j = 0; j < 4; ++j) {
        float bv = b[4 * tx + j];
        acc[0][j] = bv; acc[1][j] = bv; acc[2][j] = bv; acc[3][j] = bv;
    }
#pragma unroll 4
    for (int k = 0; k < 64; ++k) {
        float4 a4 = *(const float4*)&AsT[k * AT_STRIDE + 4 * ty];
        float4 w4 = *(const float4*)&WL[k * 64 + 4 * tx];
        float a_[4] = {a4.x, a4.y, a4.z, a4.w};
        float w_[4] = {w4.x, w4.y, w4.z, w4.w};
#pragma unroll
        for (int i = 0; i < 4; ++i)
#pragma unroll
            for (int j = 0; j < 4; ++j)
                acc[i][j] += a_[i] * w_[j];
    }
#pragma unroll
    for (int i = 0; i < 4; ++i) {
        int node = node0 + 4 * ty + i;
        if (node < NN) {
            float4 o;
            o.x = acc[i][0]; o.y = acc[i][1]; o.z = acc[i][2]; o.w = acc[i][3];
            *(float4*)&out[node * 64 + 4 * tx] = o;
        }
    }
}

// ---------------- launch ----------------

extern "C" void kernel_launch(void* const* d_in, const int* in_sizes, int n_in,
                              void* d_out, int out_size, void* d_ws, size_t ws_size,
                              hipStream_t stream) {
    const float* embed = (const float*)d_in[0];
    const float* W1s = (const float*)d_in[1];
    const float* W1n = (const float*)d_in[2];
    const float* b1  = (const float*)d_in[3];
    const float* W2s = (const float*)d_in[4];
    const float* W2n = (const float*)d_in[5];
    const float* b2  = (const float*)d_in[6];
    const float* Wfc = (const float*)d_in[7];
    const float* bfc = (const float*)d_in[8];
    const int* ids = (const int*)d_in[9];
    const int* src = (const int*)d_in[10];
    const int* dst = (const int*)d_in[11];
    float* out = (float*)d_out;

    char* ws = (char*)d_ws;
    size_t off = 0;
    auto alloc = [&](size_t nb) {
        char* p = ws + off;
        off = (off + nb + 255) & ~(size_t)255;
        return p;
    };
    int*   cnt    = (int*)alloc(NN * sizeof(int));          // needs zero
    int*   cursor = (int*)alloc(NN * sizeof(int));          // needs zero
    size_t zero_bytes = off;                                // cnt+cursor contiguous
    int*   offs    = (int*)alloc((NN + 1) * sizeof(int));
    int*   csr_src = (int*)alloc(NE * sizeof(int));
    float* x  = (float*)alloc((size_t)NN * F * sizeof(float));
    float* h1 = (float*)alloc((size_t)NN * F * sizeof(float));
    float* h2 = x;  // x is dead after layer1; reuse for h2

    hipMemsetAsync(d_ws, 0, zero_bytes, stream);

    const int TB = 256;
    k_count<<<(NE + TB - 1) / TB, TB, 0, stream>>>(dst, cnt);
    k_scan<<<1, 1024, 0, stream>>>(cnt, offs);
    k_fill<<<(NE + TB - 1) / TB, TB, 0, stream>>>(src, dst, offs, cursor, csr_src);
    k_gather<<<(NN * 16 + TB - 1) / TB, TB, 0, stream>>>(embed, ids, x);

    const int NB = (NN + 63) / 64;  // 782
    k_layer<true ><<<NB, TB, 0, stream>>>(x,  offs, csr_src, W1s, W1n, b1, h1);
    k_layer<false><<<NB, TB, 0, stream>>>(h1, offs, csr_src, W2s, W2n, b2, h2);
    k_final<<<NB, TB, 0, stream>>>(h2, Wfc, bfc, out);
}

// Round 2
// 337.108 us; speedup vs baseline: 1.5423x; 1.5423x over previous
//
#include <hip/hip_runtime.h>

#define NN 50000      // nodes
#define NE 800000     // edges
#define F  64         // feature dim
#define AT 68         // padded LDS stride (mult of 4, not mult of 32)

// ---------------- CSR build (single atomic pass) ----------------

__global__ void k_count_pos(const int* __restrict__ dst, int* __restrict__ cnt,
                            int* __restrict__ pos) {
    int e = blockIdx.x * blockDim.x + threadIdx.x;
    if (e < NE) pos[e] = atomicAdd(&cnt[dst[e]], 1);
}

__global__ void k_scan(const int* __restrict__ cnt, int* __restrict__ offs) {
    const int T = 1024, CH = 49;  // 1024*49 >= 50000
    __shared__ int sc[T];
    int t = threadIdx.x;
    int beg = t * CH;
    int s = 0;
#pragma unroll
    for (int i = 0; i < CH; ++i) {       // 49 independent loads
        int idx = beg + i;
        s += (idx < NN) ? cnt[idx] : 0;
    }
    sc[t] = s;
    __syncthreads();
    for (int d = 1; d < T; d <<= 1) {
        int v = (t >= d) ? sc[t - d] : 0;
        __syncthreads();
        sc[t] += v;
        __syncthreads();
    }
    int run = sc[t] - s;  // exclusive prefix of this chunk
#pragma unroll
    for (int i = 0; i < CH; ++i) {
        int idx = beg + i;
        if (idx < NN) { offs[idx] = run; run += cnt[idx]; }
    }
    if (t == T - 1) offs[NN] = sc[T - 1];
}

__global__ void k_fill(const int* __restrict__ src, const int* __restrict__ dst,
                       const int* __restrict__ offs, const int* __restrict__ pos,
                       int* __restrict__ csr) {
    int e = blockIdx.x * blockDim.x + threadIdx.x;
    if (e < NE) csr[offs[dst[e]] + pos[e]] = src[e];
}

// ---------------- embedding gather ----------------

__global__ void k_gather(const float* __restrict__ embed, const int* __restrict__ ids,
                         float* __restrict__ x) {
    int t = blockIdx.x * blockDim.x + threadIdx.x;  // over NN*16 float4s
    if (t < NN * 16) {
        int i = t >> 4, c = t & 15;
        ((float4*)x)[t] = ((const float4*)embed)[ids[i] * 16 + c];
    }
}

// ---------------- neighbor mean-aggregation: one wave per node ----------------
// No LDS, low VGPR -> high occupancy. Unroll-8 independent loads; tail is one
// fully-parallel round with clamped indices (no serial remainder).

__launch_bounds__(256)
__global__ void k_agg(const float* __restrict__ in, const int* __restrict__ offs,
                      const int* __restrict__ csr, float* __restrict__ hn) {
    int node = blockIdx.x * 4 + (threadIdx.x >> 6);
    int lane = threadIdx.x & 63;
    if (node >= NN) return;
    int beg = offs[node], end = offs[node + 1];
    float s = 0.f;
    int j = beg;
    for (; j + 8 <= end; j += 8) {
        int i0 = csr[j + 0], i1 = csr[j + 1], i2 = csr[j + 2], i3 = csr[j + 3];
        int i4 = csr[j + 4], i5 = csr[j + 5], i6 = csr[j + 6], i7 = csr[j + 7];
        float a0 = in[i0 * 64 + lane], a1 = in[i1 * 64 + lane];
        float a2 = in[i2 * 64 + lane], a3 = in[i3 * 64 + lane];
        float a4 = in[i4 * 64 + lane], a5 = in[i5 * 64 + lane];
        float a6 = in[i6 * 64 + lane], a7 = in[i7 * 64 + lane];
        s += ((a0 + a1) + (a2 + a3)) + ((a4 + a5) + (a6 + a7));
    }
    int rem = end - j;
    if (rem > 0) {  // one parallel round, indices clamped into valid range
        float t[8];
#pragma unroll
        for (int k = 0; k < 8; ++k) {
            int jj = (k < rem) ? j + k : j;
            float v = in[csr[jj] * 64 + lane];
            t[k] = (k < rem) ? v : 0.f;
        }
        s += ((t[0] + t[1]) + (t[2] + t[3])) + ((t[4] + t[5]) + (t[6] + t[7]));
    }
    int deg = end - beg;
    hn[node * 64 + lane] = (deg > 0) ? s * (1.f / (float)deg) : 0.f;
}

// ---------------- layer GEMM: out = act(X@Ws + Nh@Wn + b) ----------------

template <bool RELU>
__launch_bounds__(256)
__global__ void k_layer2(const float* __restrict__ X, const float* __restrict__ Nh,
                         const float* __restrict__ Ws, const float* __restrict__ Wn,
                         const float* __restrict__ b, float* __restrict__ out) {
    __shared__ float AsT[F * AT];  // transposed: [k][node]
    __shared__ float NsT[F * AT];
    __shared__ float WsL[F * F];
    __shared__ float WnL[F * F];

    const int tid = threadIdx.x;
    const int node0 = blockIdx.x * 64;

    for (int idx = tid; idx < F * F; idx += 256) {
        WsL[idx] = Ws[idx];
        WnL[idx] = Wn[idx];
    }
    // vectorized staging: 64 nodes x 16 float4s
    for (int idx = tid; idx < 64 * 16; idx += 256) {
        int n = idx >> 4, c = idx & 15;
        int node = node0 + n;
        float4 a = make_float4(0.f, 0.f, 0.f, 0.f);
        float4 v = make_float4(0.f, 0.f, 0.f, 0.f);
        if (node < NN) {
            a = ((const float4*)X)[node * 16 + c];
            v = ((const float4*)Nh)[node * 16 + c];
        }
        int f = 4 * c;
        AsT[(f + 0) * AT + n] = a.x; AsT[(f + 1) * AT + n] = a.y;
        AsT[(f + 2) * AT + n] = a.z; AsT[(f + 3) * AT + n] = a.w;
        NsT[(f + 0) * AT + n] = v.x; NsT[(f + 1) * AT + n] = v.y;
        NsT[(f + 2) * AT + n] = v.z; NsT[(f + 3) * AT + n] = v.w;
    }
    __syncthreads();

    const int tx = tid & 15, ty = tid >> 4;
    float acc[4][4];
#pragma unroll
    for (int j = 0; j < 4; ++j) {
        float bv = b[4 * tx + j];
        acc[0][j] = bv; acc[1][j] = bv; acc[2][j] = bv; acc[3][j] = bv;
    }
#pragma unroll 4
    for (int k = 0; k < 64; ++k) {
        float4 a4 = *(const float4*)&AsT[k * AT + 4 * ty];
        float4 n4 = *(const float4*)&NsT[k * AT + 4 * ty];
        float4 w4 = *(const float4*)&WsL[k * 64 + 4 * tx];
        float4 u4 = *(const float4*)&WnL[k * 64 + 4 * tx];
        float a_[4] = {a4.x, a4.y, a4.z, a4.w};
        float n_[4] = {n4.x, n4.y, n4.z, n4.w};
        float w_[4] = {w4.x, w4.y, w4.z, w4.w};
        float u_[4] = {u4.x, u4.y, u4.z, u4.w};
#pragma unroll
        for (int i = 0; i < 4; ++i)
#pragma unroll
            for (int j = 0; j < 4; ++j)
                acc[i][j] += a_[i] * w_[j] + n_[i] * u_[j];
    }

#pragma unroll
    for (int i = 0; i < 4; ++i) {
        int node = node0 + 4 * ty + i;
        if (node < NN) {
            float4 o;
            o.x = acc[i][0]; o.y = acc[i][1]; o.z = acc[i][2]; o.w = acc[i][3];
            if (RELU) {
                o.x = o.x > 0.f ? o.x : 0.f;
                o.y = o.y > 0.f ? o.y : 0.f;
                o.z = o.z > 0.f ? o.z : 0.f;
                o.w = o.w > 0.f ? o.w : 0.f;
            }
            *(float4*)&out[node * 64 + 4 * tx] = o;
        }
    }
}

// ---------------- final linear: out = H @ W_fc + b_fc ----------------

__launch_bounds__(256)
__global__ void k_final(const float* __restrict__ X, const float* __restrict__ W,
                        const float* __restrict__ b, float* __restrict__ out) {
    __shared__ float AsT[F * AT];
    __shared__ float WL[F * F];

    const int tid = threadIdx.x;
    const int node0 = blockIdx.x * 64;

    for (int idx = tid; idx < F * F; idx += 256) WL[idx] = W[idx];
    for (int idx = tid; idx < 64 * 16; idx += 256) {
        int n = idx >> 4, c = idx & 15;
        int node = node0 + n;
        float4 a = make_float4(0.f, 0.f, 0.f, 0.f);
        if (node < NN) a = ((const float4*)X)[node * 16 + c];
        int f = 4 * c;
        AsT[(f + 0) * AT + n] = a.x; AsT[(f + 1) * AT + n] = a.y;
        AsT[(f + 2) * AT + n] = a.z; AsT[(f + 3) * AT + n] = a.w;
    }
    __syncthreads();

    const int tx = tid & 15, ty = tid >> 4;
    float acc[4][4];
#pragma unroll
    for (int j = 0; j < 4; ++j) {
        float bv = b[4 * tx + j];
        acc[0][j] = bv; acc[1][j] = bv; acc[2][j] = bv; acc[3][j] = bv;
    }
#pragma unroll 4
    for (int k = 0; k < 64; ++k) {
        float4 a4 = *(const float4*)&AsT[k * AT + 4 * ty];
        float4 w4 = *(const float4*)&WL[k * 64 + 4 * tx];
        float a_[4] = {a4.x, a4.y, a4.z, a4.w};
        float w_[4] = {w4.x, w4.y, w4.z, w4.w};
#pragma unroll
        for (int i = 0; i < 4; ++i)
#pragma unroll
            for (int j = 0; j < 4; ++j)
                acc[i][j] += a_[i] * w_[j];
    }
#pragma unroll
    for (int i = 0; i < 4; ++i) {
        int node = node0 + 4 * ty + i;
        if (node < NN) {
            float4 o;
            o.x = acc[i][0]; o.y = acc[i][1]; o.z = acc[i][2]; o.w = acc[i][3];
            *(float4*)&out[node * 64 + 4 * tx] = o;
        }
    }
}

// ---------------- launch ----------------

extern "C" void kernel_launch(void* const* d_in, const int* in_sizes, int n_in,
                              void* d_out, int out_size, void* d_ws, size_t ws_size,
                              hipStream_t stream) {
    const float* embed = (const float*)d_in[0];
    const float* W1s = (const float*)d_in[1];
    const float* W1n = (const float*)d_in[2];
    const float* b1  = (const float*)d_in[3];
    const float* W2s = (const float*)d_in[4];
    const float* W2n = (const float*)d_in[5];
    const float* b2  = (const float*)d_in[6];
    const float* Wfc = (const float*)d_in[7];
    const float* bfc = (const float*)d_in[8];
    const int* ids = (const int*)d_in[9];
    const int* src = (const int*)d_in[10];
    const int* dst = (const int*)d_in[11];
    float* out = (float*)d_out;

    char* ws = (char*)d_ws;
    size_t off = 0;
    auto alloc = [&](size_t nb) {
        char* p = ws + off;
        off = (off + nb + 255) & ~(size_t)255;
        return p;
    };
    int*   cnt  = (int*)alloc(NN * sizeof(int));            // needs zero
    size_t zero_bytes = off;
    int*   offs = (int*)alloc((NN + 1) * sizeof(int));
    int*   pos  = (int*)alloc(NE * sizeof(int));
    int*   csr  = (int*)alloc(NE * sizeof(int));
    float* x    = (float*)alloc((size_t)NN * F * sizeof(float));
    float* h1   = (float*)alloc((size_t)NN * F * sizeof(float));
    float* hn   = (float*)alloc((size_t)NN * F * sizeof(float));
    float* h2   = x;  // x dead after layer-1 GEMM

    hipMemsetAsync(d_ws, 0, zero_bytes, stream);

    const int TB = 256;
    k_count_pos<<<(NE + TB - 1) / TB, TB, 0, stream>>>(dst, cnt, pos);
    k_scan<<<1, 1024, 0, stream>>>(cnt, offs);
    k_fill<<<(NE + TB - 1) / TB, TB, 0, stream>>>(src, dst, offs, pos, csr);
    k_gather<<<(NN * 16 + TB - 1) / TB, TB, 0, stream>>>(embed, ids, x);

    const int NB = (NN + 63) / 64;  // 782
    const int AB = (NN + 3) / 4;    // 12500

    k_agg<<<AB, TB, 0, stream>>>(x, offs, csr, hn);
    k_layer2<true ><<<NB, TB, 0, stream>>>(x, hn, W1s, W1n, b1, h1);
    k_agg<<<AB, TB, 0, stream>>>(h1, offs, csr, hn);
    k_layer2<false><<<NB, TB, 0, stream>>>(h1, hn, W2s, W2n, b2, h2);
    k_final<<<NB, TB, 0, stream>>>(h2, Wfc, bfc, out);
}

// Round 3
// 256.413 us; speedup vs baseline: 2.0276x; 1.3147x over previous
//
#include <hip/hip_runtime.h>

#define NN 50000      // nodes
#define NE 800000     // edges
#define F  64         // feature dim
#define AT 68         // padded LDS stride (mult of 4, not mult of 32)
#define SCAN_B 49     // scan blocks: 49 * 1024 >= 50000

// ---------------- CSR build (single atomic pass) ----------------

__global__ void k_count_pos(const int* __restrict__ dst, int* __restrict__ cnt,
                            int* __restrict__ pos) {
    int e = blockIdx.x * blockDim.x + threadIdx.x;
    if (e < NE) pos[e] = atomicAdd(&cnt[dst[e]], 1);
}

// ---- 3-phase multi-block exclusive scan of cnt[0..NN) -> offs[0..NN] ----

__launch_bounds__(256)
__global__ void k_scan_a(const int* __restrict__ cnt, int* __restrict__ partials) {
    __shared__ int sc[256];
    int t = threadIdx.x;
    int base = blockIdx.x * 1024 + t * 4;
    int s = 0;
#pragma unroll
    for (int k = 0; k < 4; ++k) {
        int idx = base + k;
        s += (idx < NN) ? cnt[idx] : 0;
    }
    sc[t] = s;
    __syncthreads();
    for (int d = 128; d > 0; d >>= 1) {
        if (t < d) sc[t] += sc[t + d];
        __syncthreads();
    }
    if (t == 0) partials[blockIdx.x] = sc[0];
}

__launch_bounds__(64)
__global__ void k_scan_b(const int* __restrict__ partials, int* __restrict__ blockoff,
                         int* __restrict__ offs_last) {
    int t = threadIdx.x;
    int v = (t < SCAN_B) ? partials[t] : 0;
    int orig = v;
    for (int d = 1; d < 64; d <<= 1) {
        int u = __shfl_up(v, d);
        if (t >= d) v += u;
    }
    if (t < SCAN_B) blockoff[t] = v - orig;  // exclusive
    if (t == 63) *offs_last = v;             // total = offs[NN]
}

__launch_bounds__(256)
__global__ void k_scan_c(const int* __restrict__ cnt, const int* __restrict__ blockoff,
                         int* __restrict__ offs) {
    __shared__ int sc[256];
    int t = threadIdx.x;
    int base = blockIdx.x * 1024 + t * 4;
    int v[4];
#pragma unroll
    for (int k = 0; k < 4; ++k) {
        int idx = base + k;
        v[k] = (idx < NN) ? cnt[idx] : 0;
    }
    int lsum = v[0] + v[1] + v[2] + v[3];
    sc[t] = lsum;
    __syncthreads();
    for (int d = 1; d < 256; d <<= 1) {
        int u = (t >= d) ? sc[t - d] : 0;
        __syncthreads();
        sc[t] += u;
        __syncthreads();
    }
    int run = blockoff[blockIdx.x] + sc[t] - lsum;  // exclusive prefix for this thread
#pragma unroll
    for (int k = 0; k < 4; ++k) {
        int idx = base + k;
        if (idx < NN) { offs[idx] = run; run += v[k]; }
    }
}

__global__ void k_fill(const int* __restrict__ src, const int* __restrict__ dst,
                       const int* __restrict__ offs, const int* __restrict__ pos,
                       int* __restrict__ csr) {
    int e = blockIdx.x * blockDim.x + threadIdx.x;
    if (e < NE) csr[offs[dst[e]] + pos[e]] = src[e];
}

// ---------------- embedding gather ----------------

__global__ void k_gather(const float* __restrict__ embed, const int* __restrict__ ids,
                         float* __restrict__ x) {
    int t = blockIdx.x * blockDim.x + threadIdx.x;  // over NN*16 float4s
    if (t < NN * 16) {
        int i = t >> 4, c = t & 15;
        ((float4*)x)[t] = ((const float4*)embed)[ids[i] * 16 + c];
    }
}

// ---------------- neighbor mean-aggregation ----------------
// thread = (node, float4 chunk): 16 lanes per node, float4 gathers.
// Unroll-8 independent rows -> 128 B/lane outstanding; tail is one clamped round.

__launch_bounds__(256)
__global__ void k_agg(const float4* __restrict__ in4, const int* __restrict__ offs,
                      const int* __restrict__ csr, float4* __restrict__ hn4) {
    int g = (blockIdx.x * 256 + threadIdx.x) >> 4;  // node
    int c = threadIdx.x & 15;                       // float4 chunk
    if (g >= NN) return;
    int beg = offs[g], end = offs[g + 1];
    float4 s = make_float4(0.f, 0.f, 0.f, 0.f);
    int j = beg;
    for (; j + 8 <= end; j += 8) {
        int i0 = csr[j + 0], i1 = csr[j + 1], i2 = csr[j + 2], i3 = csr[j + 3];
        int i4 = csr[j + 4], i5 = csr[j + 5], i6 = csr[j + 6], i7 = csr[j + 7];
        float4 v0 = in4[i0 * 16 + c], v1 = in4[i1 * 16 + c];
        float4 v2 = in4[i2 * 16 + c], v3 = in4[i3 * 16 + c];
        float4 v4 = in4[i4 * 16 + c], v5 = in4[i5 * 16 + c];
        float4 v6 = in4[i6 * 16 + c], v7 = in4[i7 * 16 + c];
        s.x += ((v0.x + v1.x) + (v2.x + v3.x)) + ((v4.x + v5.x) + (v6.x + v7.x));
        s.y += ((v0.y + v1.y) + (v2.y + v3.y)) + ((v4.y + v5.y) + (v6.y + v7.y));
        s.z += ((v0.z + v1.z) + (v2.z + v3.z)) + ((v4.z + v5.z) + (v6.z + v7.z));
        s.w += ((v0.w + v1.w) + (v2.w + v3.w)) + ((v4.w + v5.w) + (v6.w + v7.w));
    }
    int rem = end - j;
    if (rem > 0) {  // one parallel round, clamped indices
        float4 t[8];
#pragma unroll
        for (int k = 0; k < 8; ++k) {
            int jj = (k < rem) ? j + k : j;
            float4 v = in4[csr[jj] * 16 + c];
            if (k >= rem) v = make_float4(0.f, 0.f, 0.f, 0.f);
            t[k] = v;
        }
        s.x += ((t[0].x + t[1].x) + (t[2].x + t[3].x)) + ((t[4].x + t[5].x) + (t[6].x + t[7].x));
        s.y += ((t[0].y + t[1].y) + (t[2].y + t[3].y)) + ((t[4].y + t[5].y) + (t[6].y + t[7].y));
        s.z += ((t[0].z + t[1].z) + (t[2].z + t[3].z)) + ((t[4].z + t[5].z) + (t[6].z + t[7].z));
        s.w += ((t[0].w + t[1].w) + (t[2].w + t[3].w)) + ((t[4].w + t[5].w) + (t[6].w + t[7].w));
    }
    int deg = end - beg;
    float inv = (deg > 0) ? 1.f / (float)deg : 0.f;
    s.x *= inv; s.y *= inv; s.z *= inv; s.w *= inv;
    hn4[g * 16 + c] = s;
}

// ---------------- layer GEMM: out = act(X@Ws + Nh@Wn + b) ----------------

template <bool RELU>
__launch_bounds__(256)
__global__ void k_layer2(const float* __restrict__ X, const float* __restrict__ Nh,
                         const float* __restrict__ Ws, const float* __restrict__ Wn,
                         const float* __restrict__ b, float* __restrict__ out) {
    __shared__ alignas(16) float AsT[F * AT];  // transposed: [k][node]
    __shared__ alignas(16) float NsT[F * AT];
    __shared__ alignas(16) float WsL[F * F];
    __shared__ alignas(16) float WnL[F * F];

    const int tid = threadIdx.x;
    const int node0 = blockIdx.x * 64;

    for (int idx = tid; idx < F * F / 4; idx += 256) {
        ((float4*)WsL)[idx] = ((const float4*)Ws)[idx];
        ((float4*)WnL)[idx] = ((const float4*)Wn)[idx];
    }
    for (int idx = tid; idx < 64 * 16; idx += 256) {
        int n = idx >> 4, c = idx & 15;
        int node = node0 + n;
        float4 a = make_float4(0.f, 0.f, 0.f, 0.f);
        float4 v = make_float4(0.f, 0.f, 0.f, 0.f);
        if (node < NN) {
            a = ((const float4*)X)[node * 16 + c];
            v = ((const float4*)Nh)[node * 16 + c];
        }
        int f = 4 * c;
        AsT[(f + 0) * AT + n] = a.x; AsT[(f + 1) * AT + n] = a.y;
        AsT[(f + 2) * AT + n] = a.z; AsT[(f + 3) * AT + n] = a.w;
        NsT[(f + 0) * AT + n] = v.x; NsT[(f + 1) * AT + n] = v.y;
        NsT[(f + 2) * AT + n] = v.z; NsT[(f + 3) * AT + n] = v.w;
    }
    __syncthreads();

    const int tx = tid & 15, ty = tid >> 4;
    float acc[4][4];
#pragma unroll
    for (int j = 0; j < 4; ++j) {
        float bv = b[4 * tx + j];
        acc[0][j] = bv; acc[1][j] = bv; acc[2][j] = bv; acc[3][j] = bv;
    }
#pragma unroll 4
    for (int k = 0; k < 64; ++k) {
        float4 a4 = *(const float4*)&AsT[k * AT + 4 * ty];
        float4 n4 = *(const float4*)&NsT[k * AT + 4 * ty];
        float4 w4 = *(const float4*)&WsL[k * 64 + 4 * tx];
        float4 u4 = *(const float4*)&WnL[k * 64 + 4 * tx];
        float a_[4] = {a4.x, a4.y, a4.z, a4.w};
        float n_[4] = {n4.x, n4.y, n4.z, n4.w};
        float w_[4] = {w4.x, w4.y, w4.z, w4.w};
        float u_[4] = {u4.x, u4.y, u4.z, u4.w};
#pragma unroll
        for (int i = 0; i < 4; ++i)
#pragma unroll
            for (int j = 0; j < 4; ++j)
                acc[i][j] += a_[i] * w_[j] + n_[i] * u_[j];
    }

#pragma unroll
    for (int i = 0; i < 4; ++i) {
        int node = node0 + 4 * ty + i;
        if (node < NN) {
            float4 o;
            o.x = acc[i][0]; o.y = acc[i][1]; o.z = acc[i][2]; o.w = acc[i][3];
            if (RELU) {
                o.x = o.x > 0.f ? o.x : 0.f;
                o.y = o.y > 0.f ? o.y : 0.f;
                o.z = o.z > 0.f ? o.z : 0.f;
                o.w = o.w > 0.f ? o.w : 0.f;
            }
            *(float4*)&out[node * 64 + 4 * tx] = o;
        }
    }
}

// ---------------- final linear: out = H @ W_fc + b_fc ----------------

__launch_bounds__(256)
__global__ void k_final(const float* __restrict__ X, const float* __restrict__ W,
                        const float* __restrict__ b, float* __restrict__ out) {
    __shared__ alignas(16) float AsT[F * AT];
    __shared__ alignas(16) float WL[F * F];

    const int tid = threadIdx.x;
    const int node0 = blockIdx.x * 64;

    for (int idx = tid; idx < F * F / 4; idx += 256)
        ((float4*)WL)[idx] = ((const float4*)W)[idx];
    for (int idx = tid; idx < 64 * 16; idx += 256) {
        int n = idx >> 4, c = idx & 15;
        int node = node0 + n;
        float4 a = make_float4(0.f, 0.f, 0.f, 0.f);
        if (node < NN) a = ((const float4*)X)[node * 16 + c];
        int f = 4 * c;
        AsT[(f + 0) * AT + n] = a.x; AsT[(f + 1) * AT + n] = a.y;
        AsT[(f + 2) * AT + n] = a.z; AsT[(f + 3) * AT + n] = a.w;
    }
    __syncthreads();

    const int tx = tid & 15, ty = tid >> 4;
    float acc[4][4];
#pragma unroll
    for (int j = 0; j < 4; ++j) {
        float bv = b[4 * tx + j];
        acc[0][j] = bv; acc[1][j] = bv; acc[2][j] = bv; acc[3][j] = bv;
    }
#pragma unroll 4
    for (int k = 0; k < 64; ++k) {
        float4 a4 = *(const float4*)&AsT[k * AT + 4 * ty];
        float4 w4 = *(const float4*)&WL[k * 64 + 4 * tx];
        float a_[4] = {a4.x, a4.y, a4.z, a4.w};
        float w_[4] = {w4.x, w4.y, w4.z, w4.w};
#pragma unroll
        for (int i = 0; i < 4; ++i)
#pragma unroll
            for (int j = 0; j < 4; ++j)
                acc[i][j] += a_[i] * w_[j];
    }
#pragma unroll
    for (int i = 0; i < 4; ++i) {
        int node = node0 + 4 * ty + i;
        if (node < NN) {
            float4 o;
            o.x = acc[i][0]; o.y = acc[i][1]; o.z = acc[i][2]; o.w = acc[i][3];
            *(float4*)&out[node * 64 + 4 * tx] = o;
        }
    }
}

// ---------------- launch ----------------

extern "C" void kernel_launch(void* const* d_in, const int* in_sizes, int n_in,
                              void* d_out, int out_size, void* d_ws, size_t ws_size,
                              hipStream_t stream) {
    const float* embed = (const float*)d_in[0];
    const float* W1s = (const float*)d_in[1];
    const float* W1n = (const float*)d_in[2];
    const float* b1  = (const float*)d_in[3];
    const float* W2s = (const float*)d_in[4];
    const float* W2n = (const float*)d_in[5];
    const float* b2  = (const float*)d_in[6];
    const float* Wfc = (const float*)d_in[7];
    const float* bfc = (const float*)d_in[8];
    const int* ids = (const int*)d_in[9];
    const int* src = (const int*)d_in[10];
    const int* dst = (const int*)d_in[11];
    float* out = (float*)d_out;

    char* ws = (char*)d_ws;
    size_t off = 0;
    auto alloc = [&](size_t nb) {
        char* p = ws + off;
        off = (off + nb + 255) & ~(size_t)255;
        return p;
    };
    int*   cnt      = (int*)alloc(NN * sizeof(int));        // needs zero
    size_t zero_bytes = off;
    int*   offs     = (int*)alloc((NN + 1) * sizeof(int));
    int*   partials = (int*)alloc(SCAN_B * sizeof(int));
    int*   blockoff = (int*)alloc(SCAN_B * sizeof(int));
    int*   pos      = (int*)alloc(NE * sizeof(int));
    int*   csr      = (int*)alloc(NE * sizeof(int));
    float* x        = (float*)alloc((size_t)NN * F * sizeof(float));
    float* h1       = (float*)alloc((size_t)NN * F * sizeof(float));
    float* hn       = (float*)alloc((size_t)NN * F * sizeof(float));
    float* h2       = x;  // x dead after layer-1 GEMM

    hipMemsetAsync(d_ws, 0, zero_bytes, stream);

    const int TB = 256;
    k_count_pos<<<(NE + TB - 1) / TB, TB, 0, stream>>>(dst, cnt, pos);
    k_scan_a<<<SCAN_B, 256, 0, stream>>>(cnt, partials);
    k_scan_b<<<1, 64, 0, stream>>>(partials, blockoff, &offs[NN]);
    k_scan_c<<<SCAN_B, 256, 0, stream>>>(cnt, blockoff, offs);
    k_fill<<<(NE + TB - 1) / TB, TB, 0, stream>>>(src, dst, offs, pos, csr);
    k_gather<<<(NN * 16 + TB - 1) / TB, TB, 0, stream>>>(embed, ids, x);

    const int NB = (NN + 63) / 64;        // 782
    const int AB = (NN * 16 + 255) / 256; // 3125

    k_agg<<<AB, TB, 0, stream>>>((const float4*)x, offs, csr, (float4*)hn);
    k_layer2<true ><<<NB, TB, 0, stream>>>(x, hn, W1s, W1n, b1, h1);
    k_agg<<<AB, TB, 0, stream>>>((const float4*)h1, offs, csr, (float4*)hn);
    k_layer2<false><<<NB, TB, 0, stream>>>(h1, hn, W2s, W2n, b2, h2);
    k_final<<<NB, TB, 0, stream>>>(h2, Wfc, bfc, out);
}

// Round 4
// 239.077 us; speedup vs baseline: 2.1747x; 1.0725x over previous
//
#include <hip/hip_runtime.h>

#define NN 50000      // nodes
#define NE 800000     // edges
#define F  64         // feature dim
#define AT 68         // padded LDS stride (mult of 4, not mult of 32)
#define SCAN_B 49     // scan blocks: 49 * 1024 >= 50000

// bf16 round-to-nearest-even, returns low-16 bits
__device__ __forceinline__ unsigned bf16rne(float f) {
    unsigned u = __float_as_uint(f);
    return (u + 0x7fffu + ((u >> 16) & 1u)) >> 16;
}

// ---------------- CSR build (single atomic pass) ----------------

__global__ void k_count_pos(const int* __restrict__ dst, int* __restrict__ cnt,
                            int* __restrict__ pos) {
    int e = blockIdx.x * blockDim.x + threadIdx.x;
    if (e < NE) pos[e] = atomicAdd(&cnt[dst[e]], 1);
}

// ---- 3-phase multi-block exclusive scan of cnt[0..NN) -> offs[0..NN] ----

__launch_bounds__(256)
__global__ void k_scan_a(const int* __restrict__ cnt, int* __restrict__ partials) {
    __shared__ int sc[256];
    int t = threadIdx.x;
    int base = blockIdx.x * 1024 + t * 4;
    int s = 0;
#pragma unroll
    for (int k = 0; k < 4; ++k) {
        int idx = base + k;
        s += (idx < NN) ? cnt[idx] : 0;
    }
    sc[t] = s;
    __syncthreads();
    for (int d = 128; d > 0; d >>= 1) {
        if (t < d) sc[t] += sc[t + d];
        __syncthreads();
    }
    if (t == 0) partials[blockIdx.x] = sc[0];
}

__launch_bounds__(64)
__global__ void k_scan_b(const int* __restrict__ partials, int* __restrict__ blockoff,
                         int* __restrict__ offs_last) {
    int t = threadIdx.x;
    int v = (t < SCAN_B) ? partials[t] : 0;
    int orig = v;
    for (int d = 1; d < 64; d <<= 1) {
        int u = __shfl_up(v, d);
        if (t >= d) v += u;
    }
    if (t < SCAN_B) blockoff[t] = v - orig;  // exclusive
    if (t == 63) *offs_last = v;             // total = offs[NN]
}

__launch_bounds__(256)
__global__ void k_scan_c(const int* __restrict__ cnt, const int* __restrict__ blockoff,
                         int* __restrict__ offs) {
    __shared__ int sc[256];
    int t = threadIdx.x;
    int base = blockIdx.x * 1024 + t * 4;
    int v[4];
#pragma unroll
    for (int k = 0; k < 4; ++k) {
        int idx = base + k;
        v[k] = (idx < NN) ? cnt[idx] : 0;
    }
    int lsum = v[0] + v[1] + v[2] + v[3];
    sc[t] = lsum;
    __syncthreads();
    for (int d = 1; d < 256; d <<= 1) {
        int u = (t >= d) ? sc[t - d] : 0;
        __syncthreads();
        sc[t] += u;
        __syncthreads();
    }
    int run = blockoff[blockIdx.x] + sc[t] - lsum;
#pragma unroll
    for (int k = 0; k < 4; ++k) {
        int idx = base + k;
        if (idx < NN) { offs[idx] = run; run += v[k]; }
    }
}

__global__ void k_fill(const int* __restrict__ src, const int* __restrict__ dst,
                       const int* __restrict__ offs, const int* __restrict__ pos,
                       int* __restrict__ csr) {
    int e = blockIdx.x * blockDim.x + threadIdx.x;
    if (e < NE) csr[offs[dst[e]] + pos[e]] = src[e];
}

// ---------------- embedding gather: emit fp32 + bf16 copies ----------------

__global__ void k_gather(const float* __restrict__ embed, const int* __restrict__ ids,
                         float* __restrict__ x, uint2* __restrict__ xb) {
    int t = blockIdx.x * blockDim.x + threadIdx.x;  // over NN*16 float4s
    if (t < NN * 16) {
        int i = t >> 4, c = t & 15;
        float4 v = ((const float4*)embed)[ids[i] * 16 + c];
        ((float4*)x)[t] = v;
        uint2 p;
        p.x = bf16rne(v.x) | (bf16rne(v.y) << 16);
        p.y = bf16rne(v.z) | (bf16rne(v.w) << 16);
        xb[t] = p;
    }
}

// ---------------- neighbor mean-aggregation over bf16 table ----------------
// 8 lanes per node, each lane owns one uint4 (8 bf16) chunk of the 128 B row.
// fp32 accumulation. Unroll-8 rows -> 128 B/lane outstanding.

__device__ __forceinline__ void add8(float s[8], const uint4 v) {
    s[0] += __uint_as_float(v.x << 16);
    s[1] += __uint_as_float(v.x & 0xffff0000u);
    s[2] += __uint_as_float(v.y << 16);
    s[3] += __uint_as_float(v.y & 0xffff0000u);
    s[4] += __uint_as_float(v.z << 16);
    s[5] += __uint_as_float(v.z & 0xffff0000u);
    s[6] += __uint_as_float(v.w << 16);
    s[7] += __uint_as_float(v.w & 0xffff0000u);
}

__launch_bounds__(256)
__global__ void k_aggb(const uint4* __restrict__ inb, const int* __restrict__ offs,
                       const int* __restrict__ csr, float4* __restrict__ hn4) {
    int g = (blockIdx.x * 256 + threadIdx.x) >> 3;  // node
    int c = threadIdx.x & 7;                        // uint4 chunk within row
    if (g >= NN) return;
    int beg = offs[g], end = offs[g + 1];
    float s[8] = {0.f, 0.f, 0.f, 0.f, 0.f, 0.f, 0.f, 0.f};
    int j = beg;
    for (; j + 8 <= end; j += 8) {
        int i0 = csr[j + 0], i1 = csr[j + 1], i2 = csr[j + 2], i3 = csr[j + 3];
        int i4 = csr[j + 4], i5 = csr[j + 5], i6 = csr[j + 6], i7 = csr[j + 7];
        uint4 v0 = inb[i0 * 8 + c], v1 = inb[i1 * 8 + c];
        uint4 v2 = inb[i2 * 8 + c], v3 = inb[i3 * 8 + c];
        uint4 v4 = inb[i4 * 8 + c], v5 = inb[i5 * 8 + c];
        uint4 v6 = inb[i6 * 8 + c], v7 = inb[i7 * 8 + c];
        add8(s, v0); add8(s, v1); add8(s, v2); add8(s, v3);
        add8(s, v4); add8(s, v5); add8(s, v6); add8(s, v7);
    }
    int rem = end - j;
    if (rem > 0) {  // one parallel round, clamped indices
        uint4 t[8];
#pragma unroll
        for (int k = 0; k < 8; ++k) {
            int jj = (k < rem) ? j + k : j;
            t[k] = inb[csr[jj] * 8 + c];
        }
#pragma unroll
        for (int k = 0; k < 8; ++k)
            if (k < rem) add8(s, t[k]);
    }
    int deg = end - beg;
    float inv = (deg > 0) ? 1.f / (float)deg : 0.f;
    float4 o0 = make_float4(s[0] * inv, s[1] * inv, s[2] * inv, s[3] * inv);
    float4 o1 = make_float4(s[4] * inv, s[5] * inv, s[6] * inv, s[7] * inv);
    hn4[g * 16 + c * 2 + 0] = o0;
    hn4[g * 16 + c * 2 + 1] = o1;
}

// ---------------- layer GEMM: out = act(X@Ws + Nh@Wn + b) ----------------
// EMITB: also emit bf16 copy of the output (for the next layer's aggregation).

template <bool RELU, bool EMITB>
__launch_bounds__(256)
__global__ void k_layer2(const float* __restrict__ X, const float* __restrict__ Nh,
                         const float* __restrict__ Ws, const float* __restrict__ Wn,
                         const float* __restrict__ b, float* __restrict__ out,
                         uint2* __restrict__ outb) {
    __shared__ alignas(16) float AsT[F * AT];  // transposed: [k][node]
    __shared__ alignas(16) float NsT[F * AT];
    __shared__ alignas(16) float WsL[F * F];
    __shared__ alignas(16) float WnL[F * F];

    const int tid = threadIdx.x;
    const int node0 = blockIdx.x * 64;

    for (int idx = tid; idx < F * F / 4; idx += 256) {
        ((float4*)WsL)[idx] = ((const float4*)Ws)[idx];
        ((float4*)WnL)[idx] = ((const float4*)Wn)[idx];
    }
    for (int idx = tid; idx < 64 * 16; idx += 256) {
        int n = idx >> 4, c = idx & 15;
        int node = node0 + n;
        float4 a = make_float4(0.f, 0.f, 0.f, 0.f);
        float4 v = make_float4(0.f, 0.f, 0.f, 0.f);
        if (node < NN) {
            a = ((const float4*)X)[node * 16 + c];
            v = ((const float4*)Nh)[node * 16 + c];
        }
        int f = 4 * c;
        AsT[(f + 0) * AT + n] = a.x; AsT[(f + 1) * AT + n] = a.y;
        AsT[(f + 2) * AT + n] = a.z; AsT[(f + 3) * AT + n] = a.w;
        NsT[(f + 0) * AT + n] = v.x; NsT[(f + 1) * AT + n] = v.y;
        NsT[(f + 2) * AT + n] = v.z; NsT[(f + 3) * AT + n] = v.w;
    }
    __syncthreads();

    const int tx = tid & 15, ty = tid >> 4;
    float acc[4][4];
#pragma unroll
    for (int j = 0; j < 4; ++j) {
        float bv = b[4 * tx + j];
        acc[0][j] = bv; acc[1][j] = bv; acc[2][j] = bv; acc[3][j] = bv;
    }
#pragma unroll 4
    for (int k = 0; k < 64; ++k) {
        float4 a4 = *(const float4*)&AsT[k * AT + 4 * ty];
        float4 n4 = *(const float4*)&NsT[k * AT + 4 * ty];
        float4 w4 = *(const float4*)&WsL[k * 64 + 4 * tx];
        float4 u4 = *(const float4*)&WnL[k * 64 + 4 * tx];
        float a_[4] = {a4.x, a4.y, a4.z, a4.w};
        float n_[4] = {n4.x, n4.y, n4.z, n4.w};
        float w_[4] = {w4.x, w4.y, w4.z, w4.w};
        float u_[4] = {u4.x, u4.y, u4.z, u4.w};
#pragma unroll
        for (int i = 0; i < 4; ++i)
#pragma unroll
            for (int j = 0; j < 4; ++j)
                acc[i][j] += a_[i] * w_[j] + n_[i] * u_[j];
    }

#pragma unroll
    for (int i = 0; i < 4; ++i) {
        int node = node0 + 4 * ty + i;
        if (node < NN) {
            float4 o;
            o.x = acc[i][0]; o.y = acc[i][1]; o.z = acc[i][2]; o.w = acc[i][3];
            if (RELU) {
                o.x = o.x > 0.f ? o.x : 0.f;
                o.y = o.y > 0.f ? o.y : 0.f;
                o.z = o.z > 0.f ? o.z : 0.f;
                o.w = o.w > 0.f ? o.w : 0.f;
            }
            *(float4*)&out[node * 64 + 4 * tx] = o;
            if (EMITB) {
                uint2 p;
                p.x = bf16rne(o.x) | (bf16rne(o.y) << 16);
                p.y = bf16rne(o.z) | (bf16rne(o.w) << 16);
                outb[node * 16 + tx] = p;
            }
        }
    }
}

// ---------------- final linear: out = H @ W_fc + b_fc ----------------

__launch_bounds__(256)
__global__ void k_final(const float* __restrict__ X, const float* __restrict__ W,
                        const float* __restrict__ b, float* __restrict__ out) {
    __shared__ alignas(16) float AsT[F * AT];
    __shared__ alignas(16) float WL[F * F];

    const int tid = threadIdx.x;
    const int node0 = blockIdx.x * 64;

    for (int idx = tid; idx < F * F / 4; idx += 256)
        ((float4*)WL)[idx] = ((const float4*)W)[idx];
    for (int idx = tid; idx < 64 * 16; idx += 256) {
        int n = idx >> 4, c = idx & 15;
        int node = node0 + n;
        float4 a = make_float4(0.f, 0.f, 0.f, 0.f);
        if (node < NN) a = ((const float4*)X)[node * 16 + c];
        int f = 4 * c;
        AsT[(f + 0) * AT + n] = a.x; AsT[(f + 1) * AT + n] = a.y;
        AsT[(f + 2) * AT + n] = a.z; AsT[(f + 3) * AT + n] = a.w;
    }
    __syncthreads();

    const int tx = tid & 15, ty = tid >> 4;
    float acc[4][4];
#pragma unroll
    for (int j = 0; j < 4; ++j) {
        float bv = b[4 * tx + j];
        acc[0][j] = bv; acc[1][j] = bv; acc[2][j] = bv; acc[3][j] = bv;
    }
#pragma unroll 4
    for (int k = 0; k < 64; ++k) {
        float4 a4 = *(const float4*)&AsT[k * AT + 4 * ty];
        float4 w4 = *(const float4*)&WL[k * 64 + 4 * tx];
        float a_[4] = {a4.x, a4.y, a4.z, a4.w};
        float w_[4] = {w4.x, w4.y, w4.z, w4.w};
#pragma unroll
        for (int i = 0; i < 4; ++i)
#pragma unroll
            for (int j = 0; j < 4; ++j)
                acc[i][j] += a_[i] * w_[j];
    }
#pragma unroll
    for (int i = 0; i < 4; ++i) {
        int node = node0 + 4 * ty + i;
        if (node < NN) {
            float4 o;
            o.x = acc[i][0]; o.y = acc[i][1]; o.z = acc[i][2]; o.w = acc[i][3];
            *(float4*)&out[node * 64 + 4 * tx] = o;
        }
    }
}

// ---------------- launch ----------------

extern "C" void kernel_launch(void* const* d_in, const int* in_sizes, int n_in,
                              void* d_out, int out_size, void* d_ws, size_t ws_size,
                              hipStream_t stream) {
    const float* embed = (const float*)d_in[0];
    const float* W1s = (const float*)d_in[1];
    const float* W1n = (const float*)d_in[2];
    const float* b1  = (const float*)d_in[3];
    const float* W2s = (const float*)d_in[4];
    const float* W2n = (const float*)d_in[5];
    const float* b2  = (const float*)d_in[6];
    const float* Wfc = (const float*)d_in[7];
    const float* bfc = (const float*)d_in[8];
    const int* ids = (const int*)d_in[9];
    const int* src = (const int*)d_in[10];
    const int* dst = (const int*)d_in[11];
    float* out = (float*)d_out;

    char* ws = (char*)d_ws;
    size_t off = 0;
    auto alloc = [&](size_t nb) {
        char* p = ws + off;
        off = (off + nb + 255) & ~(size_t)255;
        return p;
    };
    int*   cnt      = (int*)alloc(NN * sizeof(int));        // needs zero
    size_t zero_bytes = off;
    int*   offs     = (int*)alloc((NN + 1) * sizeof(int));
    int*   partials = (int*)alloc(SCAN_B * sizeof(int));
    int*   blockoff = (int*)alloc(SCAN_B * sizeof(int));
    int*   pos      = (int*)alloc(NE * sizeof(int));
    int*   csr      = (int*)alloc(NE * sizeof(int));
    float* x        = (float*)alloc((size_t)NN * F * sizeof(float));
    float* h1       = (float*)alloc((size_t)NN * F * sizeof(float));
    float* hn       = (float*)alloc((size_t)NN * F * sizeof(float));
    uint2* xb       = (uint2*)alloc((size_t)NN * 16 * sizeof(uint2));  // bf16 x
    uint2* h1b      = (uint2*)alloc((size_t)NN * 16 * sizeof(uint2));  // bf16 h1
    float* h2       = x;  // x dead after layer-1 GEMM

    hipMemsetAsync(d_ws, 0, zero_bytes, stream);

    const int TB = 256;
    k_count_pos<<<(NE + TB - 1) / TB, TB, 0, stream>>>(dst, cnt, pos);
    k_scan_a<<<SCAN_B, 256, 0, stream>>>(cnt, partials);
    k_scan_b<<<1, 64, 0, stream>>>(partials, blockoff, &offs[NN]);
    k_scan_c<<<SCAN_B, 256, 0, stream>>>(cnt, blockoff, offs);
    k_fill<<<(NE + TB - 1) / TB, TB, 0, stream>>>(src, dst, offs, pos, csr);
    k_gather<<<(NN * 16 + TB - 1) / TB, TB, 0, stream>>>(embed, ids, x, xb);

    const int NB = (NN + 63) / 64;       // 782
    const int AB = (NN * 8 + 255) / 256; // 1563

    k_aggb<<<AB, TB, 0, stream>>>((const uint4*)xb, offs, csr, (float4*)hn);
    k_layer2<true, true><<<NB, TB, 0, stream>>>(x, hn, W1s, W1n, b1, h1, h1b);
    k_aggb<<<AB, TB, 0, stream>>>((const uint4*)h1b, offs, csr, (float4*)hn);
    k_layer2<false, false><<<NB, TB, 0, stream>>>(h1, hn, W2s, W2n, b2, h2, nullptr);
    k_final<<<NB, TB, 0, stream>>>(h2, Wfc, bfc, out);
}